// Round 1
// baseline (272.074 us; speedup 1.0000x reference)
//
#include <hip/hip_runtime.h>

// ---------------- problem constants ----------------
#define N_NODES 10000
#define IN_DIM  512
#define OUT_DIM 128
#define NE      262144
#define K_DIM   10000

// ---------------- GEMM2 (adj @ h) tiling ----------------
#define BM 64
#define BN 128
#define BK 64
#define SPLITS 4
#define KSTEPS_TOTAL 157      // ceil(10000/64)
#define STEPS_PER_SPLIT 40    // 40+40+40+37 = 157

typedef __attribute__((ext_vector_type(8))) __bf16 bf16x8;
typedef __attribute__((ext_vector_type(4))) float  f32x4;

__device__ inline ushort f2bf(float f) {
    // round-to-nearest-even f32 -> bf16 (no NaN in this data)
    uint u = __float_as_uint(f);
    return (ushort)((u + 0x7fffu + ((u >> 16) & 1u)) >> 16);
}
__device__ inline float bf2f(ushort s) {
    return __uint_as_float(((uint)s) << 16);
}

// ---------------- kernel 1: hT[c][r] = (x @ W)[r][c] in bf16 ----------------
__global__ __launch_bounds__(256) void k_xw(const float* __restrict__ x,
                                            const float* __restrict__ w,
                                            ushort* __restrict__ hT) {
    __shared__ float xs[16][IN_DIM];   // 32 KB
    const int r0 = blockIdx.x * 16;
    const int tid = threadIdx.x;

    for (int q = tid; q < 16 * IN_DIM / 4; q += 256) {
        int row = q >> 7;               // 128 float4 per row
        int k4  = (q & 127) << 2;
        int gr  = r0 + row;
        float4 val = make_float4(0.f, 0.f, 0.f, 0.f);
        if (gr < N_NODES) val = *(const float4*)(x + (size_t)gr * IN_DIM + k4);
        *(float4*)&xs[row][k4] = val;
    }
    __syncthreads();

    const int c0 = (tid & 63) * 2;      // two adjacent output cols
    const int rg = tid >> 6;            // 4 row-groups of 4 rows
    float acc[4][2] = {};

    for (int k = 0; k < IN_DIM; k += 4) {
        float wc[4][2];
#pragma unroll
        for (int kk = 0; kk < 4; ++kk) {
            wc[kk][0] = w[(k + kk) * OUT_DIM + c0];
            wc[kk][1] = w[(k + kk) * OUT_DIM + c0 + 1];
        }
#pragma unroll
        for (int r = 0; r < 4; ++r) {
            float4 xv = *(const float4*)&xs[rg * 4 + r][k];
            float xa[4] = {xv.x, xv.y, xv.z, xv.w};
#pragma unroll
            for (int kk = 0; kk < 4; ++kk) {
                acc[r][0] += xa[kk] * wc[kk][0];
                acc[r][1] += xa[kk] * wc[kk][1];
            }
        }
    }
#pragma unroll
    for (int r = 0; r < 4; ++r) {
        int gr = r0 + rg * 4 + r;
        if (gr < N_NODES) {
            hT[(size_t)c0 * N_NODES + gr]       = f2bf(acc[r][0]);
            hT[(size_t)(c0 + 1) * N_NODES + gr] = f2bf(acc[r][1]);
        }
    }
}

// ---------------- kernel 2: v = W2 @ w3[:128]  (256 floats) ----------------
__global__ void k_v(const float* __restrict__ w2, const float* __restrict__ w3,
                    float* __restrict__ v) {
    int t = threadIdx.x;   // 256 threads
    float s = 0.f;
    for (int j = 0; j < OUT_DIM; ++j) s += w2[t * OUT_DIM + j] * w3[j];
    v[t] = s;
}

// ---------------- kernel 3: z_part[split] = adj[:, ks] @ h[ks, :] (bf16 MFMA) ----------------
__global__ __launch_bounds__(256) void k_adj(const float* __restrict__ adj,
                                             const ushort* __restrict__ hT,
                                             float* __restrict__ zp) {
    __shared__ ushort As[BM][BK + 8];   // 64 x 72 bf16, stride 144 B
    __shared__ ushort Bs[BN][BK + 8];   // 128 x 72 bf16

    const int m0    = blockIdx.x * BM;
    const int split = blockIdx.y;
    const int tid   = threadIdx.x;
    const int step0 = split * STEPS_PER_SPLIT;
    const int step1 = min(step0 + STEPS_PER_SPLIT, KSTEPS_TOTAL);

    const int wave = tid >> 6, lane = tid & 63;
    const int wm = wave >> 1, wn = wave & 1;     // 2x2 waves, wave tile 32x64
    const int lr = lane & 15, lg = lane >> 4;

    f32x4 acc[2][4];
#pragma unroll
    for (int i = 0; i < 2; ++i)
#pragma unroll
        for (int j = 0; j < 4; ++j) acc[i][j] = (f32x4){0.f, 0.f, 0.f, 0.f};

    for (int st = step0; st < step1; ++st) {
        const int k0 = st * BK;

        // load A chunk (adj, f32) into regs: 1024 float4, 4/thread
        float4 av[4];
#pragma unroll
        for (int q = 0; q < 4; ++q) {
            int c = tid + q * 256;
            int row = c >> 4, kc = (c & 15) << 2;
            int gm = m0 + row, gk = k0 + kc;
            float4 val = make_float4(0.f, 0.f, 0.f, 0.f);
            if (gm < N_NODES && gk < K_DIM)
                val = *(const float4*)(adj + (size_t)gm * K_DIM + gk);
            av[q] = val;
        }
        // load B chunk (hT, bf16) into regs: 1024 x 16B, 4/thread
        uint4 bv[4];
#pragma unroll
        for (int q = 0; q < 4; ++q) {
            int c = tid + q * 256;
            int n = c >> 3, kc = (c & 7) << 3;
            int gk = k0 + kc;
            uint4 val = make_uint4(0u, 0u, 0u, 0u);
            if (gk < K_DIM)
                val = *(const uint4*)(hT + (size_t)n * K_DIM + gk);
            bv[q] = val;
        }

        __syncthreads();   // previous iteration's LDS reads done
#pragma unroll
        for (int q = 0; q < 4; ++q) {
            int c = tid + q * 256;
            int row = c >> 4, kc = (c & 15) << 2;
            ushort4 ap;
            ap.x = f2bf(av[q].x); ap.y = f2bf(av[q].y);
            ap.z = f2bf(av[q].z); ap.w = f2bf(av[q].w);
            *(ushort4*)&As[row][kc] = ap;
        }
#pragma unroll
        for (int q = 0; q < 4; ++q) {
            int c = tid + q * 256;
            int n = c >> 3, kc = (c & 7) << 3;
            *(uint4*)&Bs[n][kc] = bv[q];
        }
        __syncthreads();

#pragma unroll
        for (int kh = 0; kh < 2; ++kh) {
            bf16x8 af[2], bfr[4];
#pragma unroll
            for (int mf = 0; mf < 2; ++mf)
                af[mf] = *(const bf16x8*)&As[wm * 32 + mf * 16 + lr][kh * 32 + lg * 8];
#pragma unroll
            for (int nf = 0; nf < 4; ++nf)
                bfr[nf] = *(const bf16x8*)&Bs[wn * 64 + nf * 16 + lr][kh * 32 + lg * 8];
#pragma unroll
            for (int mf = 0; mf < 2; ++mf)
#pragma unroll
                for (int nf = 0; nf < 4; ++nf)
                    acc[mf][nf] = __builtin_amdgcn_mfma_f32_16x16x32_bf16(
                        af[mf], bfr[nf], acc[mf][nf], 0, 0, 0);
        }
    }

    float* out = zp + (size_t)split * N_NODES * OUT_DIM;
#pragma unroll
    for (int mf = 0; mf < 2; ++mf)
#pragma unroll
        for (int nf = 0; nf < 4; ++nf)
#pragma unroll
            for (int r = 0; r < 4; ++r) {
                int row = m0 + wm * 32 + mf * 16 + lg * 4 + r;
                int col = wn * 64 + nf * 16 + lr;
                if (row < N_NODES)
                    out[(size_t)row * OUT_DIM + col] = acc[mf][nf][r];
            }
}

// ---------------- kernel 4: reduce splits + per-node precompute ----------------
__global__ __launch_bounds__(256) void k_node(const float* __restrict__ zp,
                                              const float* __restrict__ v,
                                              const float* __restrict__ w3,
                                              float* __restrict__ a,
                                              float* __restrict__ b,
                                              ushort* __restrict__ zb,
                                              ushort* __restrict__ zwb) {
    const int wave = threadIdx.x >> 6, lane = threadIdx.x & 63;
    const int i = blockIdx.x * 4 + wave;
    if (i >= N_NODES) return;
    const int k0 = lane, k1 = lane + 64;

    float z0 = 0.f, z1 = 0.f;
#pragma unroll
    for (int s = 0; s < SPLITS; ++s) {
        const float* row = zp + ((size_t)s * N_NODES + i) * OUT_DIM;
        z0 += row[k0];
        z1 += row[k1];
    }
    zb[(size_t)i * OUT_DIM + k0]  = f2bf(z0);
    zb[(size_t)i * OUT_DIM + k1]  = f2bf(z1);
    zwb[(size_t)i * OUT_DIM + k0] = f2bf(z0 * w3[OUT_DIM + k0]);
    zwb[(size_t)i * OUT_DIM + k1] = f2bf(z1 * w3[OUT_DIM + k1]);

    float ra = fmaxf(z0, 0.f) * v[k0] + fmaxf(z1, 0.f) * v[k1];
    float rb = fmaxf(z0, 0.f) * v[OUT_DIM + k0] + fmaxf(z1, 0.f) * v[OUT_DIM + k1];
#pragma unroll
    for (int off = 32; off; off >>= 1) {
        ra += __shfl_down(ra, off);
        rb += __shfl_down(rb, off);
    }
    if (lane == 0) { a[i] = ra; b[i] = rb; }
}

// ---------------- kernel 5: per-edge logit + sigmoid ----------------
__global__ __launch_bounds__(256) void k_edge(const int* __restrict__ e_true,
                                              const int* __restrict__ e_false,
                                              const float* __restrict__ a,
                                              const float* __restrict__ b,
                                              const ushort* __restrict__ zb,
                                              const ushort* __restrict__ zwb,
                                              float* __restrict__ out) {
    const int lane = threadIdx.x & 63;
    const int gwave = (blockIdx.x * blockDim.x + threadIdx.x) >> 6;
    const int nwaves = (gridDim.x * blockDim.x) >> 6;

    for (int e = gwave; e < 2 * NE; e += nwaves) {
        int2 ij = (e < NE) ? ((const int2*)e_true)[e] : ((const int2*)e_false)[e - NE];
        int i = ij.x, j = ij.y;

        uint zwi = *(const uint*)(zwb + (size_t)i * OUT_DIM + 2 * lane);
        uint zj  = *(const uint*)(zb  + (size_t)j * OUT_DIM + 2 * lane);
        float d = bf2f((ushort)(zwi & 0xffffu)) * bf2f((ushort)(zj & 0xffffu))
                + bf2f((ushort)(zwi >> 16))     * bf2f((ushort)(zj >> 16));
#pragma unroll
        for (int off = 32; off; off >>= 1) d += __shfl_down(d, off);
        if (lane == 0) {
            float logit = a[i] + b[j] + d;
            out[e] = 1.0f / (1.0f + __expf(-logit));
        }
    }
}

// ---------------- launch ----------------
extern "C" void kernel_launch(void* const* d_in, const int* in_sizes, int n_in,
                              void* d_out, int out_size, void* d_ws, size_t ws_size,
                              hipStream_t stream) {
    const float* x      = (const float*)d_in[0];
    const float* adj    = (const float*)d_in[1];
    const float* w      = (const float*)d_in[2];
    const float* w2     = (const float*)d_in[3];
    const float* w3     = (const float*)d_in[4];
    const int* e_true   = (const int*)d_in[5];
    const int* e_false  = (const int*)d_in[6];
    float* out          = (float*)d_out;

    char* ws = (char*)d_ws;
    // workspace layout (bytes)
    ushort* hT  = (ushort*)(ws);                        //   2,560,000  (128 x 10000 bf16)
    float*  zp  = (float*)(ws + 2560000);               //  20,480,000  (4 x 10000 x 128 f32)
    float*  v   = (float*)(ws + 23040000);              //       1,024
    float*  a   = (float*)(ws + 23041024);              //      40,000
    float*  b   = (float*)(ws + 23081024);              //      40,000
    ushort* zb  = (ushort*)(ws + 23121024);             //   2,560,000
    ushort* zwb = (ushort*)(ws + 25681024);             //   2,560,000  -> total ~28.2 MB

    k_xw<<<625, 256, 0, stream>>>(x, w, hT);
    k_v<<<1, 256, 0, stream>>>(w2, w3, v);
    k_adj<<<dim3(157, SPLITS), 256, 0, stream>>>(adj, hT, zp);
    k_node<<<2500, 256, 0, stream>>>(zp, v, w3, a, b, zb, zwb);
    k_edge<<<2048, 256, 0, stream>>>(e_true, e_false, a, b, zb, zwb, out);
}